// Round 3
// baseline (612.602 us; speedup 1.0000x reference)
//
#include <hip/hip_runtime.h>
#include <hip/hip_bf16.h>

namespace {
constexpr int kN = 50000;
constexpr int kD = 256;
constexpr int kPos = 32;
constexpr int kNeg = 20;
constexpr float kEps = 1e-15f;
constexpr int kSlots = kPos / 4 + kNeg / 4;  // 13 neighbors per 16-lane group

// ---------- fp32 -> bf16 table conversion; also zeroes the accumulators ----------
__global__ __launch_bounds__(256) void convert_kernel(const float* __restrict__ emb,
                                                      ushort* __restrict__ tbl,
                                                      float* __restrict__ acc) {
    if (blockIdx.x == 0 && threadIdx.x < 4) acc[threadIdx.x] = 0.f;  // num, den, counter, pad
    const size_t i = ((size_t)blockIdx.x * 256 + threadIdx.x) * 8;  // 8 floats/thread
    const float4* src = reinterpret_cast<const float4*>(emb + i);
    const float4 a = src[0];
    const float4 b = src[1];
    __hip_bfloat16 h[8];
    h[0] = __float2bfloat16(a.x); h[1] = __float2bfloat16(a.y);
    h[2] = __float2bfloat16(a.z); h[3] = __float2bfloat16(a.w);
    h[4] = __float2bfloat16(b.x); h[5] = __float2bfloat16(b.y);
    h[6] = __float2bfloat16(b.z); h[7] = __float2bfloat16(b.w);
    *reinterpret_cast<uint4*>(tbl + i) = *reinterpret_cast<const uint4*>(h);
}

__device__ __forceinline__ float bf16_dot_pair(unsigned u, float e0, float e1, float d) {
    d = fmaf(__uint_as_float(u << 16), e0, d);
    d = fmaf(__uint_as_float(u & 0xffff0000u), e1, d);
    return d;
}

// One wave per row; wave = 4 groups x 16 lanes. Each group owns 13 neighbor
// slots (8 pos + 5 neg), processed branch-free in double-buffered batches of 4
// so ~8-16 gather loads stay in flight per wave (latency hiding), each load
// instruction covering 256 B contiguous.
__global__ __launch_bounds__(256) void row_loss_bf16(
    const float* __restrict__ emb,
    const ushort* __restrict__ tbl,
    const int* __restrict__ nbr,
    const int* __restrict__ nbrm,
    const int* __restrict__ neg,
    const int* __restrict__ rmask,
    float* __restrict__ acc,
    float* __restrict__ out) {
    __shared__ float s_num[4];
    __shared__ float s_den[4];
    const int wave = threadIdx.x >> 6;
    const int lane = threadIdx.x & 63;
    const int n = blockIdx.x * 4 + wave;
    const int g = lane >> 4;
    const int t = lane & 15;

    const int rm = rmask[n];
    float num = 0.f;

    if (rm) {
        // own row fp32, element order matching lane t's bf16 chunks:
        // elems [8t..8t+7] and [128+8t..128+8t+7]
        const float4* erow = reinterpret_cast<const float4*>(emb + (size_t)n * kD);
        const float4 f0 = erow[2 * t];
        const float4 f1 = erow[2 * t + 1];
        const float4 f2 = erow[32 + 2 * t];
        const float4 f3 = erow[33 + 2 * t];
        const float own[16] = {f0.x, f0.y, f0.z, f0.w, f1.x, f1.y, f1.z, f1.w,
                               f2.x, f2.y, f2.z, f2.w, f3.x, f3.y, f3.z, f3.w};

        const int* nrow = nbr + (size_t)n * kPos;
        const int* mrow = nbrm + (size_t)n * kPos;
        const int* grow = neg + (size_t)n * kNeg;

        int idx[kSlots];
        float w[kPos / 4];
#pragma unroll
        for (int s = 0; s < kPos / 4; ++s) {
            idx[s] = nrow[s * 4 + g];
            w[s] = (float)mrow[s * 4 + g];
        }
#pragma unroll
        for (int s = 0; s < kNeg / 4; ++s) idx[kPos / 4 + s] = grow[s * 4 + g];

        float pos_sum = 0.f, neg_sum = 0.f, cnt = 0.f;
#pragma unroll
        for (int s = 0; s < kPos / 4; ++s) cnt += w[s];

        // double-buffered batches of 4 slots: {0-3},{4-7},{8-11},{12}
        uint4 buf[2][4][2];
#pragma unroll
        for (int s = 0; s < 4; ++s) {
            const uint4* rp = reinterpret_cast<const uint4*>(tbl + (size_t)idx[s] * kD);
            buf[0][s][0] = rp[t];
            buf[0][s][1] = rp[16 + t];
        }
#pragma unroll
        for (int b = 0; b < 4; ++b) {
            const int cur = b & 1;
            const int nxt = cur ^ 1;
            if (b < 3) {
#pragma unroll
                for (int s = 0; s < 4; ++s) {
                    const int slot = (b + 1) * 4 + s;
                    if (slot < kSlots) {
                        const uint4* rp =
                            reinterpret_cast<const uint4*>(tbl + (size_t)idx[slot] * kD);
                        buf[nxt][s][0] = rp[t];
                        buf[nxt][s][1] = rp[16 + t];
                    }
                }
            }
#pragma unroll
            for (int s = 0; s < 4; ++s) {
                const int slot = b * 4 + s;
                if (slot < kSlots) {
                    const uint4 u0 = buf[cur][s][0];
                    const uint4 u1 = buf[cur][s][1];
                    float d = 0.f;
                    d = bf16_dot_pair(u0.x, own[0], own[1], d);
                    d = bf16_dot_pair(u0.y, own[2], own[3], d);
                    d = bf16_dot_pair(u0.z, own[4], own[5], d);
                    d = bf16_dot_pair(u0.w, own[6], own[7], d);
                    d = bf16_dot_pair(u1.x, own[8], own[9], d);
                    d = bf16_dot_pair(u1.y, own[10], own[11], d);
                    d = bf16_dot_pair(u1.z, own[12], own[13], d);
                    d = bf16_dot_pair(u1.w, own[14], own[15], d);
                    d += __shfl_xor(d, 8);
                    d += __shfl_xor(d, 4);
                    d += __shfl_xor(d, 2);
                    d += __shfl_xor(d, 1);
                    const float sg = 1.f / (1.f + __expf(-d));
                    if (slot < kPos / 4) {
                        pos_sum += -__logf(sg + kEps) * w[slot];
                    } else {
                        neg_sum += -__logf(1.f - sg + kEps);
                    }
                }
            }
        }

        // combine the 4 groups (each group's lanes hold identical values)
        pos_sum += __shfl_xor(pos_sum, 16);
        pos_sum += __shfl_xor(pos_sum, 32);
        neg_sum += __shfl_xor(neg_sum, 16);
        neg_sum += __shfl_xor(neg_sum, 32);
        cnt += __shfl_xor(cnt, 16);
        cnt += __shfl_xor(cnt, 32);

        if (cnt > 0.f) num = pos_sum / cnt + neg_sum / (float)kNeg;
        // cnt==0 -> NaN row in reference -> replaced by 0 -> contributes 0
    }

    if (lane == 0) {
        s_num[wave] = num;
        s_den[wave] = (float)rm;
    }
    __syncthreads();
    if (threadIdx.x == 0) {
        atomicAdd(&acc[0], s_num[0] + s_num[1] + s_num[2] + s_num[3]);
        atomicAdd(&acc[1], s_den[0] + s_den[1] + s_den[2] + s_den[3]);
        __threadfence();
        const unsigned done = atomicAdd(reinterpret_cast<unsigned*>(&acc[2]), 1u);
        if (done == gridDim.x - 1) {
            // atomic RMW reads are device-coherent across XCDs
            const float a0 = atomicAdd(&acc[0], 0.f);
            const float a1 = atomicAdd(&acc[1], 0.f);
            out[0] = a0 / a1;
        }
    }
}

// ---------- fp32 fallback (if d_ws can't hold the bf16 table) ----------
__global__ __launch_bounds__(256) void row_loss_f32(
    const float* __restrict__ emb,
    const int* __restrict__ nbr,
    const int* __restrict__ nbrm,
    const int* __restrict__ neg,
    const int* __restrict__ rmask,
    float* __restrict__ acc) {
    __shared__ float s_num[4];
    __shared__ float s_den[4];
    const int wave = threadIdx.x >> 6;
    const int lane = threadIdx.x & 63;
    const int n = blockIdx.x * 4 + wave;
    const int g = lane >> 4;
    const int t = lane & 15;

    const int rm = rmask[n];
    float num = 0.f;

    if (rm) {
        const float4* erow = reinterpret_cast<const float4*>(emb + (size_t)n * kD);
        float4 own4[4];
#pragma unroll
        for (int j = 0; j < 4; ++j) own4[j] = erow[j * 16 + t];

        const int* nrow = nbr + (size_t)n * kPos;
        const int* mrow = nbrm + (size_t)n * kPos;
        const int* grow = neg + (size_t)n * kNeg;

        float pos_sum = 0.f, neg_sum = 0.f, cnt = 0.f;

#pragma unroll
        for (int it = 0; it < kPos / 4; ++it) {
            const int idx = nrow[it * 4 + g];
            const float mf = (float)mrow[it * 4 + g];
            cnt += mf;
            const float4* brow = reinterpret_cast<const float4*>(emb + (size_t)idx * kD);
            float d = 0.f;
#pragma unroll
            for (int j = 0; j < 4; ++j) {
                const float4 b = brow[j * 16 + t];
                const float4 a = own4[j];
                d += a.x * b.x + a.y * b.y + a.z * b.z + a.w * b.w;
            }
            d += __shfl_xor(d, 8);
            d += __shfl_xor(d, 4);
            d += __shfl_xor(d, 2);
            d += __shfl_xor(d, 1);
            const float s = 1.f / (1.f + __expf(-d));
            pos_sum += -__logf(s + kEps) * mf;
        }

#pragma unroll
        for (int it = 0; it < kNeg / 4; ++it) {
            const int idx = grow[it * 4 + g];
            const float4* brow = reinterpret_cast<const float4*>(emb + (size_t)idx * kD);
            float d = 0.f;
#pragma unroll
            for (int j = 0; j < 4; ++j) {
                const float4 b = brow[j * 16 + t];
                const float4 a = own4[j];
                d += a.x * b.x + a.y * b.y + a.z * b.z + a.w * b.w;
            }
            d += __shfl_xor(d, 8);
            d += __shfl_xor(d, 4);
            d += __shfl_xor(d, 2);
            d += __shfl_xor(d, 1);
            const float s = 1.f / (1.f + __expf(-d));
            neg_sum += -__logf(1.f - s + kEps);
        }

        pos_sum += __shfl_xor(pos_sum, 16);
        pos_sum += __shfl_xor(pos_sum, 32);
        neg_sum += __shfl_xor(neg_sum, 16);
        neg_sum += __shfl_xor(neg_sum, 32);
        cnt += __shfl_xor(cnt, 16);
        cnt += __shfl_xor(cnt, 32);

        if (cnt > 0.f) num = pos_sum / cnt + neg_sum / (float)kNeg;
    }

    if (lane == 0) {
        s_num[wave] = num;
        s_den[wave] = (float)rm;
    }
    __syncthreads();
    if (threadIdx.x == 0) {
        atomicAdd(&acc[0], s_num[0] + s_num[1] + s_num[2] + s_num[3]);
        atomicAdd(&acc[1], s_den[0] + s_den[1] + s_den[2] + s_den[3]);
    }
}

__global__ void finalize_kernel(const float* __restrict__ acc, float* __restrict__ out) {
    out[0] = acc[0] / acc[1];
}
}  // namespace

extern "C" void kernel_launch(void* const* d_in, const int* in_sizes, int n_in,
                              void* d_out, int out_size, void* d_ws, size_t ws_size,
                              hipStream_t stream) {
    const float* emb = (const float*)d_in[0];
    const int* nbr = (const int*)d_in[1];
    const int* nbrm = (const int*)d_in[2];
    const int* neg = (const int*)d_in[3];
    const int* rmask = (const int*)d_in[4];
    float* acc = (float*)d_ws;

    const size_t tbl_bytes = (size_t)kN * kD * sizeof(ushort);
    if (ws_size >= 256 + tbl_bytes) {
        ushort* tbl = (ushort*)((char*)d_ws + 256);
        convert_kernel<<<kN * kD / 8 / 256, 256, 0, stream>>>(emb, tbl, acc);
        row_loss_bf16<<<kN / 4, 256, 0, stream>>>(emb, tbl, nbr, nbrm, neg, rmask, acc,
                                                  (float*)d_out);
    } else {
        hipMemsetAsync(acc, 0, 2 * sizeof(float), stream);
        row_loss_f32<<<kN / 4, 256, 0, stream>>>(emb, nbr, nbrm, neg, rmask, acc);
        finalize_kernel<<<1, 1, 0, stream>>>(acc, (float*)d_out);
    }
}

// Round 4
// 433.375 us; speedup vs baseline: 1.4136x; 1.4136x over previous
//
#include <hip/hip_runtime.h>
#include <hip/hip_bf16.h>

namespace {
constexpr int kN = 50000;
constexpr int kD = 256;
constexpr int kPos = 32;
constexpr int kNeg = 20;
constexpr float kEps = 1e-15f;
constexpr int kSlots = kPos / 4 + kNeg / 4;  // 13 neighbors per 16-lane group
constexpr int kNBuf = 4;                     // ring stages in flight
constexpr int kStageBytes = 4 * 512;         // 4 groups x 512 B bf16 row

// ---------- fp32 -> bf16 table conversion ----------
__global__ __launch_bounds__(256) void convert_kernel(const float* __restrict__ emb,
                                                      ushort* __restrict__ tbl) {
    const size_t i = ((size_t)blockIdx.x * 256 + threadIdx.x) * 8;  // 8 floats/thread
    const float4* src = reinterpret_cast<const float4*>(emb + i);
    const float4 a = src[0];
    const float4 b = src[1];
    __hip_bfloat16 h[8];
    h[0] = __float2bfloat16(a.x); h[1] = __float2bfloat16(a.y);
    h[2] = __float2bfloat16(a.z); h[3] = __float2bfloat16(a.w);
    h[4] = __float2bfloat16(b.x); h[5] = __float2bfloat16(b.y);
    h[6] = __float2bfloat16(b.z); h[7] = __float2bfloat16(b.w);
    *reinterpret_cast<uint4*>(tbl + i) = *reinterpret_cast<const uint4*>(h);
}

__device__ __forceinline__ float bf16_dot_pair(unsigned u, float e0, float e1, float d) {
    d = fmaf(__uint_as_float(u << 16), e0, d);
    d = fmaf(__uint_as_float(u & 0xffff0000u), e1, d);
    return d;
}

// Async gather: global_load_lds (16 B/lane, 1 KiB/wave-instr), 2 instrs per stage.
#define ISSUE_STAGE(S)                                                                   \
    do {                                                                                 \
        if ((S) < kSlots) {                                                              \
            char* stg = my_ring + ((S) % kNBuf) * kStageBytes;                           \
            const char* gsrc = tblb + (size_t)idx[(S)] * 512 + t * 16;                   \
            __builtin_amdgcn_global_load_lds(                                            \
                (const __attribute__((address_space(1))) void*)gsrc,                     \
                (__attribute__((address_space(3))) void*)stg, 16, 0, 0);                 \
            __builtin_amdgcn_global_load_lds(                                            \
                (const __attribute__((address_space(1))) void*)(gsrc + 256),             \
                (__attribute__((address_space(3))) void*)(stg + 1024), 16, 0, 0);        \
        }                                                                                \
    } while (0)

#define WAIT_VM(N) asm volatile("s_waitcnt vmcnt(" #N ")" ::: "memory")

#define DO_SLOT(S, VM)                                                                   \
    do {                                                                                 \
        WAIT_VM(VM);                                                                     \
        const char* stg = my_ring + ((S) % kNBuf) * kStageBytes;                         \
        const uint4 u0 = *reinterpret_cast<const uint4*>(stg + g * 256 + t * 16);        \
        const uint4 u1 = *reinterpret_cast<const uint4*>(stg + 1024 + g * 256 + t * 16); \
        float d = 0.f;                                                                   \
        d = bf16_dot_pair(u0.x, own[0], own[1], d);                                      \
        d = bf16_dot_pair(u0.y, own[2], own[3], d);                                      \
        d = bf16_dot_pair(u0.z, own[4], own[5], d);                                      \
        d = bf16_dot_pair(u0.w, own[6], own[7], d);                                      \
        d = bf16_dot_pair(u1.x, own[8], own[9], d);                                      \
        d = bf16_dot_pair(u1.y, own[10], own[11], d);                                    \
        d = bf16_dot_pair(u1.z, own[12], own[13], d);                                    \
        d = bf16_dot_pair(u1.w, own[14], own[15], d);                                    \
        d += __shfl_xor(d, 8);                                                           \
        d += __shfl_xor(d, 4);                                                           \
        d += __shfl_xor(d, 2);                                                           \
        d += __shfl_xor(d, 1);                                                           \
        const float sg = 1.f / (1.f + __expf(-d));                                       \
        if ((S) < kPos / 4) {                                                            \
            pos_sum += -__logf(sg + kEps) * w[(S)];                                      \
        } else {                                                                         \
            neg_sum += -__logf(1.f - sg + kEps);                                         \
        }                                                                                \
    } while (0)

// One wave per row; wave = 4 groups x 16 lanes, 13 slots per group, async
// ring-buffered through LDS so up to 8 gather loads stay in flight per wave.
__global__ __launch_bounds__(256) void row_loss_bf16(
    const float* __restrict__ emb,
    const ushort* __restrict__ tbl,
    const int* __restrict__ nbr,
    const int* __restrict__ nbrm,
    const int* __restrict__ neg,
    const int* __restrict__ rmask,
    float* __restrict__ acc) {
    __shared__ __align__(16) char ring[4][kNBuf * kStageBytes];  // 32 KiB
    __shared__ float s_num[4];
    __shared__ float s_den[4];
    const int wave = threadIdx.x >> 6;
    const int lane = threadIdx.x & 63;
    const int n = blockIdx.x * 4 + wave;
    const int g = lane >> 4;
    const int t = lane & 15;
    char* my_ring = ring[wave];
    const char* tblb = reinterpret_cast<const char*>(tbl);

    const int rm = rmask[n];
    float num = 0.f;

    if (rm) {
        // own row fp32, element order matching lane t's bf16 chunks:
        // elems [8t..8t+7] and [128+8t..128+8t+7]
        const float4* erow = reinterpret_cast<const float4*>(emb + (size_t)n * kD);
        const float4 f0 = erow[2 * t];
        const float4 f1 = erow[2 * t + 1];
        const float4 f2 = erow[32 + 2 * t];
        const float4 f3 = erow[33 + 2 * t];
        const float own[16] = {f0.x, f0.y, f0.z, f0.w, f1.x, f1.y, f1.z, f1.w,
                               f2.x, f2.y, f2.z, f2.w, f3.x, f3.y, f3.z, f3.w};

        const int* nrow = nbr + (size_t)n * kPos;
        const int* mrow = nbrm + (size_t)n * kPos;
        const int* grow = neg + (size_t)n * kNeg;

        int idx[kSlots];
        float w[kPos / 4];
        float cnt = 0.f;
#pragma unroll
        for (int s = 0; s < kPos / 4; ++s) {
            const int m = mrow[s * 4 + g];
            w[s] = (float)m;
            cnt += (float)m;
            // masked slot -> gather own row (cache-hot); weight-0 term is exactly 0
            idx[s] = m ? nrow[s * 4 + g] : n;
        }
#pragma unroll
        for (int s = 0; s < kNeg / 4; ++s) idx[kPos / 4 + s] = grow[s * 4 + g];

        float pos_sum = 0.f, neg_sum = 0.f;

        ISSUE_STAGE(0);
        ISSUE_STAGE(1);
        ISSUE_STAGE(2);
        ISSUE_STAGE(3);
        DO_SLOT(0, 6);  ISSUE_STAGE(4);
        DO_SLOT(1, 6);  ISSUE_STAGE(5);
        DO_SLOT(2, 6);  ISSUE_STAGE(6);
        DO_SLOT(3, 6);  ISSUE_STAGE(7);
        DO_SLOT(4, 6);  ISSUE_STAGE(8);
        DO_SLOT(5, 6);  ISSUE_STAGE(9);
        DO_SLOT(6, 6);  ISSUE_STAGE(10);
        DO_SLOT(7, 6);  ISSUE_STAGE(11);
        DO_SLOT(8, 6);  ISSUE_STAGE(12);
        DO_SLOT(9, 6);
        DO_SLOT(10, 4);
        DO_SLOT(11, 2);
        DO_SLOT(12, 0);

        // combine the 4 groups (each group's lanes hold identical values)
        pos_sum += __shfl_xor(pos_sum, 16);
        pos_sum += __shfl_xor(pos_sum, 32);
        neg_sum += __shfl_xor(neg_sum, 16);
        neg_sum += __shfl_xor(neg_sum, 32);
        cnt += __shfl_xor(cnt, 16);
        cnt += __shfl_xor(cnt, 32);

        if (cnt > 0.f) num = pos_sum / cnt + neg_sum / (float)kNeg;
        // cnt==0 -> NaN row in reference -> replaced by 0 -> contributes 0
    }

    if (lane == 0) {
        s_num[wave] = num;
        s_den[wave] = (float)rm;
    }
    __syncthreads();
    if (threadIdx.x == 0) {
        atomicAdd(&acc[0], s_num[0] + s_num[1] + s_num[2] + s_num[3]);
        atomicAdd(&acc[1], s_den[0] + s_den[1] + s_den[2] + s_den[3]);
    }
}

// ---------- fp32 fallback (if d_ws can't hold the bf16 table) ----------
__global__ __launch_bounds__(256) void row_loss_f32(
    const float* __restrict__ emb,
    const int* __restrict__ nbr,
    const int* __restrict__ nbrm,
    const int* __restrict__ neg,
    const int* __restrict__ rmask,
    float* __restrict__ acc) {
    __shared__ float s_num[4];
    __shared__ float s_den[4];
    const int wave = threadIdx.x >> 6;
    const int lane = threadIdx.x & 63;
    const int n = blockIdx.x * 4 + wave;
    const int g = lane >> 4;
    const int t = lane & 15;

    const int rm = rmask[n];
    float num = 0.f;

    if (rm) {
        const float4* erow = reinterpret_cast<const float4*>(emb + (size_t)n * kD);
        float4 own4[4];
#pragma unroll
        for (int j = 0; j < 4; ++j) own4[j] = erow[j * 16 + t];

        const int* nrow = nbr + (size_t)n * kPos;
        const int* mrow = nbrm + (size_t)n * kPos;
        const int* grow = neg + (size_t)n * kNeg;

        float pos_sum = 0.f, neg_sum = 0.f, cnt = 0.f;

#pragma unroll
        for (int it = 0; it < kPos / 4; ++it) {
            const int idx = nrow[it * 4 + g];
            const float mf = (float)mrow[it * 4 + g];
            cnt += mf;
            const float4* brow = reinterpret_cast<const float4*>(emb + (size_t)idx * kD);
            float d = 0.f;
#pragma unroll
            for (int j = 0; j < 4; ++j) {
                const float4 b = brow[j * 16 + t];
                const float4 a = own4[j];
                d += a.x * b.x + a.y * b.y + a.z * b.z + a.w * b.w;
            }
            d += __shfl_xor(d, 8);
            d += __shfl_xor(d, 4);
            d += __shfl_xor(d, 2);
            d += __shfl_xor(d, 1);
            const float s = 1.f / (1.f + __expf(-d));
            pos_sum += -__logf(s + kEps) * mf;
        }

#pragma unroll
        for (int it = 0; it < kNeg / 4; ++it) {
            const int idx = grow[it * 4 + g];
            const float4* brow = reinterpret_cast<const float4*>(emb + (size_t)idx * kD);
            float d = 0.f;
#pragma unroll
            for (int j = 0; j < 4; ++j) {
                const float4 b = brow[j * 16 + t];
                const float4 a = own4[j];
                d += a.x * b.x + a.y * b.y + a.z * b.z + a.w * b.w;
            }
            d += __shfl_xor(d, 8);
            d += __shfl_xor(d, 4);
            d += __shfl_xor(d, 2);
            d += __shfl_xor(d, 1);
            const float s = 1.f / (1.f + __expf(-d));
            neg_sum += -__logf(1.f - s + kEps);
        }

        pos_sum += __shfl_xor(pos_sum, 16);
        pos_sum += __shfl_xor(pos_sum, 32);
        neg_sum += __shfl_xor(neg_sum, 16);
        neg_sum += __shfl_xor(neg_sum, 32);
        cnt += __shfl_xor(cnt, 16);
        cnt += __shfl_xor(cnt, 32);

        if (cnt > 0.f) num = pos_sum / cnt + neg_sum / (float)kNeg;
    }

    if (lane == 0) {
        s_num[wave] = num;
        s_den[wave] = (float)rm;
    }
    __syncthreads();
    if (threadIdx.x == 0) {
        atomicAdd(&acc[0], s_num[0] + s_num[1] + s_num[2] + s_num[3]);
        atomicAdd(&acc[1], s_den[0] + s_den[1] + s_den[2] + s_den[3]);
    }
}

__global__ void finalize_kernel(const float* __restrict__ acc, float* __restrict__ out) {
    out[0] = acc[0] / acc[1];
}
}  // namespace

extern "C" void kernel_launch(void* const* d_in, const int* in_sizes, int n_in,
                              void* d_out, int out_size, void* d_ws, size_t ws_size,
                              hipStream_t stream) {
    const float* emb = (const float*)d_in[0];
    const int* nbr = (const int*)d_in[1];
    const int* nbrm = (const int*)d_in[2];
    const int* neg = (const int*)d_in[3];
    const int* rmask = (const int*)d_in[4];
    float* acc = (float*)d_ws;

    hipMemsetAsync(acc, 0, 2 * sizeof(float), stream);

    const size_t tbl_bytes = (size_t)kN * kD * sizeof(ushort);
    if (ws_size >= 256 + tbl_bytes) {
        ushort* tbl = (ushort*)((char*)d_ws + 256);
        convert_kernel<<<kN * kD / 8 / 256, 256, 0, stream>>>(emb, tbl);
        row_loss_bf16<<<kN / 4, 256, 0, stream>>>(emb, tbl, nbr, nbrm, neg, rmask, acc);
    } else {
        row_loss_f32<<<kN / 4, 256, 0, stream>>>(emb, nbr, nbrm, neg, rmask, acc);
    }
    finalize_kernel<<<1, 1, 0, stream>>>(acc, (float*)d_out);
}

// Round 5
// 430.359 us; speedup vs baseline: 1.4235x; 1.0070x over previous
//
#include <hip/hip_runtime.h>
#include <hip/hip_bf16.h>

#ifndef __has_builtin
#define __has_builtin(x) 0
#endif
#if __has_builtin(__builtin_amdgcn_cvt_pk_f32_fp8) && __has_builtin(__builtin_amdgcn_cvt_pk_fp8_f32)
#define HAVE_FP8_CVT 1
#else
#define HAVE_FP8_CVT 0
#endif

namespace {
constexpr int kN = 50000;
constexpr int kD = 256;
constexpr int kPos = 32;
constexpr int kNeg = 20;
constexpr float kEps = 1e-15f;

typedef float floatx2 __attribute__((ext_vector_type(2)));

#if HAVE_FP8_CVT
// ---------- fp32 -> fp8 e4m3 table conversion; also zeroes the accumulators ----------
// 16 elems/thread: read 64 B, write 16 B. Grid covers kN*kD exactly.
__global__ __launch_bounds__(256) void convert_fp8(const float* __restrict__ emb,
                                                   uint* __restrict__ tbl,
                                                   float* __restrict__ acc) {
    if (blockIdx.x == 0 && threadIdx.x < 4) acc[threadIdx.x] = 0.f;
    const size_t i = ((size_t)blockIdx.x * 256 + threadIdx.x) * 16;
    const float4* src = reinterpret_cast<const float4*>(emb + i);
    uint4 o;
    {
        const float4 a = src[0], b = src[1];
        uint v = 0;
        v = __builtin_amdgcn_cvt_pk_fp8_f32(a.x, a.y, v, false);
        v = __builtin_amdgcn_cvt_pk_fp8_f32(a.z, a.w, v, true);
        o.x = v;
        v = 0;
        v = __builtin_amdgcn_cvt_pk_fp8_f32(b.x, b.y, v, false);
        v = __builtin_amdgcn_cvt_pk_fp8_f32(b.z, b.w, v, true);
        o.y = v;
    }
    {
        const float4 a = src[2], b = src[3];
        uint v = 0;
        v = __builtin_amdgcn_cvt_pk_fp8_f32(a.x, a.y, v, false);
        v = __builtin_amdgcn_cvt_pk_fp8_f32(a.z, a.w, v, true);
        o.z = v;
        v = 0;
        v = __builtin_amdgcn_cvt_pk_fp8_f32(b.x, b.y, v, false);
        v = __builtin_amdgcn_cvt_pk_fp8_f32(b.z, b.w, v, true);
        o.w = v;
    }
    reinterpret_cast<uint4*>(tbl)[i / 16] = o;
}

__device__ __forceinline__ void dq4(uint u, const float* o, float& d) {
    const floatx2 p0 = __builtin_amdgcn_cvt_pk_f32_fp8(u, false);
    const floatx2 p1 = __builtin_amdgcn_cvt_pk_f32_fp8(u, true);
    d = fmaf(p0.x, o[0], d);
    d = fmaf(p0.y, o[1], d);
    d = fmaf(p1.x, o[2], d);
    d = fmaf(p1.y, o[3], d);
}

// One wave per row; wave = 4 groups x 16 lanes, one neighbor per group per
// iteration. fp8 row = 256 B; lane t loads one uint4 (elems 16t..16t+15), so
// each gather instruction covers 4 rows x 256 B = 16 full cache lines.
__global__ __launch_bounds__(256) void row_loss_fp8(
    const uchar* __restrict__ tblb,
    const int* __restrict__ nbr,
    const int* __restrict__ nbrm,
    const int* __restrict__ neg,
    const int* __restrict__ rmask,
    float* __restrict__ acc) {
    __shared__ float s_num[4];
    __shared__ float s_den[4];
    const int wave = threadIdx.x >> 6;
    const int lane = threadIdx.x & 63;
    const int n = blockIdx.x * 4 + wave;
    const int g = lane >> 4;
    const int t = lane & 15;

    const int rm = rmask[n];
    float num = 0.f;

    if (rm) {
        // own row, dequantized once into registers (elems 16t..16t+15)
        float own[16];
        {
            const uint4 ou =
                *reinterpret_cast<const uint4*>(tblb + (size_t)n * 256 + t * 16);
            floatx2 p;
            p = __builtin_amdgcn_cvt_pk_f32_fp8(ou.x, false); own[0] = p.x; own[1] = p.y;
            p = __builtin_amdgcn_cvt_pk_f32_fp8(ou.x, true);  own[2] = p.x; own[3] = p.y;
            p = __builtin_amdgcn_cvt_pk_f32_fp8(ou.y, false); own[4] = p.x; own[5] = p.y;
            p = __builtin_amdgcn_cvt_pk_f32_fp8(ou.y, true);  own[6] = p.x; own[7] = p.y;
            p = __builtin_amdgcn_cvt_pk_f32_fp8(ou.z, false); own[8] = p.x; own[9] = p.y;
            p = __builtin_amdgcn_cvt_pk_f32_fp8(ou.z, true);  own[10] = p.x; own[11] = p.y;
            p = __builtin_amdgcn_cvt_pk_f32_fp8(ou.w, false); own[12] = p.x; own[13] = p.y;
            p = __builtin_amdgcn_cvt_pk_f32_fp8(ou.w, true);  own[14] = p.x; own[15] = p.y;
        }

        const int* nrow = nbr + (size_t)n * kPos;
        const int* mrow = nbrm + (size_t)n * kPos;
        const int* grow = neg + (size_t)n * kNeg;

        float pos_sum = 0.f, neg_sum = 0.f, cnt = 0.f;

#pragma unroll
        for (int it = 0; it < kPos / 4; ++it) {
            const int idx = nrow[it * 4 + g];
            const int m = mrow[it * 4 + g];
            cnt += (float)m;
            if (m) {  // group-uniform: masked slot skips the gather entirely
                const uint4 u =
                    *reinterpret_cast<const uint4*>(tblb + (size_t)idx * 256 + t * 16);
                float d = 0.f;
                dq4(u.x, own + 0, d);
                dq4(u.y, own + 4, d);
                dq4(u.z, own + 8, d);
                dq4(u.w, own + 12, d);
                d += __shfl_xor(d, 8);
                d += __shfl_xor(d, 4);
                d += __shfl_xor(d, 2);
                d += __shfl_xor(d, 1);
                const float s = 1.f / (1.f + __expf(-d));
                pos_sum += -__logf(s + kEps);
            }
        }

#pragma unroll
        for (int it = 0; it < kNeg / 4; ++it) {
            const int idx = grow[it * 4 + g];
            const uint4 u =
                *reinterpret_cast<const uint4*>(tblb + (size_t)idx * 256 + t * 16);
            float d = 0.f;
            dq4(u.x, own + 0, d);
            dq4(u.y, own + 4, d);
            dq4(u.z, own + 8, d);
            dq4(u.w, own + 12, d);
            d += __shfl_xor(d, 8);
            d += __shfl_xor(d, 4);
            d += __shfl_xor(d, 2);
            d += __shfl_xor(d, 1);
            const float s = 1.f / (1.f + __expf(-d));
            neg_sum += -__logf(1.f - s + kEps);
        }

        // combine the 4 groups (each group's 16 lanes hold identical values)
        pos_sum += __shfl_xor(pos_sum, 16);
        pos_sum += __shfl_xor(pos_sum, 32);
        neg_sum += __shfl_xor(neg_sum, 16);
        neg_sum += __shfl_xor(neg_sum, 32);
        cnt += __shfl_xor(cnt, 16);
        cnt += __shfl_xor(cnt, 32);

        if (cnt > 0.f) num = pos_sum / cnt + neg_sum / (float)kNeg;
        // cnt==0 -> NaN row in reference -> replaced by 0 -> contributes 0
    }

    if (lane == 0) {
        s_num[wave] = num;
        s_den[wave] = (float)rm;
    }
    __syncthreads();
    if (threadIdx.x == 0) {
        atomicAdd(&acc[0], s_num[0] + s_num[1] + s_num[2] + s_num[3]);
        atomicAdd(&acc[1], s_den[0] + s_den[1] + s_den[2] + s_den[3]);
    }
}
#endif  // HAVE_FP8_CVT

// ---------- bf16 fallback path (R2 structure; used only if fp8 cvt missing) ----------
__global__ __launch_bounds__(256) void convert_bf16(const float* __restrict__ emb,
                                                    ushort* __restrict__ tbl,
                                                    float* __restrict__ acc) {
    if (blockIdx.x == 0 && threadIdx.x < 4) acc[threadIdx.x] = 0.f;
    const size_t i = ((size_t)blockIdx.x * 256 + threadIdx.x) * 8;
    const float4* src = reinterpret_cast<const float4*>(emb + i);
    const float4 a = src[0];
    const float4 b = src[1];
    __hip_bfloat16 h[8];
    h[0] = __float2bfloat16(a.x); h[1] = __float2bfloat16(a.y);
    h[2] = __float2bfloat16(a.z); h[3] = __float2bfloat16(a.w);
    h[4] = __float2bfloat16(b.x); h[5] = __float2bfloat16(b.y);
    h[6] = __float2bfloat16(b.z); h[7] = __float2bfloat16(b.w);
    *reinterpret_cast<uint4*>(tbl + i) = *reinterpret_cast<const uint4*>(h);
}

__device__ __forceinline__ float bf16_dot_pair(unsigned u, float e0, float e1, float d) {
    d = fmaf(__uint_as_float(u << 16), e0, d);
    d = fmaf(__uint_as_float(u & 0xffff0000u), e1, d);
    return d;
}

__global__ __launch_bounds__(256) void row_loss_bf16(
    const float* __restrict__ emb,
    const ushort* __restrict__ tbl,
    const int* __restrict__ nbr,
    const int* __restrict__ nbrm,
    const int* __restrict__ neg,
    const int* __restrict__ rmask,
    float* __restrict__ acc) {
    __shared__ float s_num[4];
    __shared__ float s_den[4];
    const int wave = threadIdx.x >> 6;
    const int lane = threadIdx.x & 63;
    const int n = blockIdx.x * 4 + wave;
    const int g = lane >> 4;
    const int t = lane & 15;

    const int rm = rmask[n];
    float num = 0.f;

    if (rm) {
        const float4* erow = reinterpret_cast<const float4*>(emb + (size_t)n * kD);
        const float4 f0 = erow[2 * t];
        const float4 f1 = erow[2 * t + 1];
        const float4 f2 = erow[32 + 2 * t];
        const float4 f3 = erow[33 + 2 * t];
        const float own[16] = {f0.x, f0.y, f0.z, f0.w, f1.x, f1.y, f1.z, f1.w,
                               f2.x, f2.y, f2.z, f2.w, f3.x, f3.y, f3.z, f3.w};

        const int* nrow = nbr + (size_t)n * kPos;
        const int* mrow = nbrm + (size_t)n * kPos;
        const int* grow = neg + (size_t)n * kNeg;

        float pos_sum = 0.f, neg_sum = 0.f, cnt = 0.f;

#pragma unroll
        for (int it = 0; it < kPos / 4; ++it) {
            const int idx = nrow[it * 4 + g];
            const int m = mrow[it * 4 + g];
            cnt += (float)m;
            if (m) {
                const uint4* rp = reinterpret_cast<const uint4*>(tbl + (size_t)idx * kD);
                const uint4 u0 = rp[t];
                const uint4 u1 = rp[16 + t];
                float d = 0.f;
                d = bf16_dot_pair(u0.x, own[0], own[1], d);
                d = bf16_dot_pair(u0.y, own[2], own[3], d);
                d = bf16_dot_pair(u0.z, own[4], own[5], d);
                d = bf16_dot_pair(u0.w, own[6], own[7], d);
                d = bf16_dot_pair(u1.x, own[8], own[9], d);
                d = bf16_dot_pair(u1.y, own[10], own[11], d);
                d = bf16_dot_pair(u1.z, own[12], own[13], d);
                d = bf16_dot_pair(u1.w, own[14], own[15], d);
                d += __shfl_xor(d, 8);
                d += __shfl_xor(d, 4);
                d += __shfl_xor(d, 2);
                d += __shfl_xor(d, 1);
                const float s = 1.f / (1.f + __expf(-d));
                pos_sum += -__logf(s + kEps);
            }
        }

#pragma unroll
        for (int it = 0; it < kNeg / 4; ++it) {
            const int idx = grow[it * 4 + g];
            const uint4* rp = reinterpret_cast<const uint4*>(tbl + (size_t)idx * kD);
            const uint4 u0 = rp[t];
            const uint4 u1 = rp[16 + t];
            float d = 0.f;
            d = bf16_dot_pair(u0.x, own[0], own[1], d);
            d = bf16_dot_pair(u0.y, own[2], own[3], d);
            d = bf16_dot_pair(u0.z, own[4], own[5], d);
            d = bf16_dot_pair(u0.w, own[6], own[7], d);
            d = bf16_dot_pair(u1.x, own[8], own[9], d);
            d = bf16_dot_pair(u1.y, own[10], own[11], d);
            d = bf16_dot_pair(u1.z, own[12], own[13], d);
            d = bf16_dot_pair(u1.w, own[14], own[15], d);
            d += __shfl_xor(d, 8);
            d += __shfl_xor(d, 4);
            d += __shfl_xor(d, 2);
            d += __shfl_xor(d, 1);
            const float s = 1.f / (1.f + __expf(-d));
            neg_sum += -__logf(1.f - s + kEps);
        }

        pos_sum += __shfl_xor(pos_sum, 16);
        pos_sum += __shfl_xor(pos_sum, 32);
        neg_sum += __shfl_xor(neg_sum, 16);
        neg_sum += __shfl_xor(neg_sum, 32);
        cnt += __shfl_xor(cnt, 16);
        cnt += __shfl_xor(cnt, 32);

        if (cnt > 0.f) num = pos_sum / cnt + neg_sum / (float)kNeg;
    }

    if (lane == 0) {
        s_num[wave] = num;
        s_den[wave] = (float)rm;
    }
    __syncthreads();
    if (threadIdx.x == 0) {
        atomicAdd(&acc[0], s_num[0] + s_num[1] + s_num[2] + s_num[3]);
        atomicAdd(&acc[1], s_den[0] + s_den[1] + s_den[2] + s_den[3]);
    }
}

__global__ void finalize_kernel(const float* __restrict__ acc, float* __restrict__ out) {
    out[0] = acc[0] / acc[1];
}
}  // namespace

extern "C" void kernel_launch(void* const* d_in, const int* in_sizes, int n_in,
                              void* d_out, int out_size, void* d_ws, size_t ws_size,
                              hipStream_t stream) {
    const float* emb = (const float*)d_in[0];
    const int* nbr = (const int*)d_in[1];
    const int* nbrm = (const int*)d_in[2];
    const int* neg = (const int*)d_in[3];
    const int* rmask = (const int*)d_in[4];
    float* acc = (float*)d_ws;

#if HAVE_FP8_CVT
    const size_t tbl_bytes = (size_t)kN * kD;  // 1 B/elem
    if (ws_size >= 256 + tbl_bytes) {
        uint* tbl = (uint*)((char*)d_ws + 256);
        convert_fp8<<<kN * kD / 16 / 256, 256, 0, stream>>>(emb, tbl, acc);
        row_loss_fp8<<<kN / 4, 256, 0, stream>>>((const uchar*)tbl, nbr, nbrm, neg,
                                                 rmask, acc);
        finalize_kernel<<<1, 1, 0, stream>>>(acc, (float*)d_out);
        return;
    }
#endif
    {
        ushort* tbl = (ushort*)((char*)d_ws + 256);
        convert_bf16<<<kN * kD / 8 / 256, 256, 0, stream>>>(emb, tbl, acc);
        row_loss_bf16<<<kN / 4, 256, 0, stream>>>(emb, tbl, nbr, nbrm, neg, rmask, acc);
        finalize_kernel<<<1, 1, 0, stream>>>(acc, (float*)d_out);
    }
}